// Round 1
// baseline (995.301 us; speedup 1.0000x reference)
//
#include <hip/hip_runtime.h>

// CRF-as-RNN mean-field on MI355X.
// B=2, L=21, C=3, H=W=96, N=9216, NITERS=5.
//
// Math: A[n][m] = exp(-0.5*D)/rowsum, D = sq[n]+sq[m]-2 f_n.f_m.
// Factor: exp(-0.5 D) = exp(-0.5 sq[n]) * exp(g[m] + f_n.f_m), g[m] = -0.5 sq[m].
// The row-constant factor cancels under row normalization, so we use
// w[n][m] = exp2( gs[m] + f_n . fs[m] )  (pre-scaled by log2(e)),
// rowsum[n] = sum_m w[n][m]  (iteration-invariant, computed once),
// per iter:  P[l][n] = sum_m w[n][m] * MQ[l][m];  msg = P / rowsum;
//            Q = softmax_l(-(E0 + msg));  MQ = Mu @ Q  (general Mu, matches ref).

#define BB 2
#define LL 21
#define NNPX 9216           // 96*96
#define NITERS 5
#define LOG2E 1.4426950408889634f

// ---------------- prep: features + Q0 + MQ0 ----------------
__global__ __launch_bounds__(256) void k_prep(
        const float* __restrict__ E0, const float* __restrict__ Refs,
        const float* __restrict__ Mu,
        float4* __restrict__ FN, float4* __restrict__ FS,
        float* __restrict__ MQ) {
    __shared__ float muS[LL * LL];
    for (int i = threadIdx.x; i < LL * LL; i += 256) muS[i] = Mu[i];
    __syncthreads();

    int idx = blockIdx.x * 256 + threadIdx.x;      // b*N + n
    int b = idx / NNPX, n = idx % NNPX;

    const float* rb = Refs + (size_t)b * 3 * NNPX + n;
    float r0 = rb[0], r1 = rb[NNPX], r2 = rb[2 * NNPX];
    FN[idx] = make_float4(r0, r1, r2, 0.f);
    float g = -0.5f * (r0 * r0 + r1 * r1 + r2 * r2);
    FS[idx] = make_float4(g * LOG2E, r0 * LOG2E, r1 * LOG2E, r2 * LOG2E);

    // Q0 = softmax_l(-E0)
    const float* eb = E0 + (size_t)b * LL * NNPX + n;
    float x[LL];
    float mx = -1e30f;
    for (int l = 0; l < LL; ++l) { x[l] = -eb[(size_t)l * NNPX]; mx = fmaxf(mx, x[l]); }
    float s = 0.f;
    for (int l = 0; l < LL; ++l) { x[l] = __builtin_amdgcn_exp2f((x[l] - mx) * LOG2E); s += x[l]; }
    float rs = __builtin_amdgcn_rcpf(s);
    for (int l = 0; l < LL; ++l) x[l] *= rs;

    // MQ0 = Mu @ Q0
    float* mq = MQ + (size_t)b * LL * NNPX + n;
    for (int k = 0; k < LL; ++k) {
        float a = 0.f;
        for (int l = 0; l < LL; ++l) a += muS[k * LL + l] * x[l];
        mq[(size_t)k * NNPX] = a;
    }
}

// ---------------- rowsum: one wave per row ----------------
__global__ __launch_bounds__(256) void k_rowsum(
        const float4* __restrict__ FS, const float4* __restrict__ FN,
        float* __restrict__ rowsum) {
    int r = blockIdx.x * 4 + (threadIdx.x >> 6);   // global row id = b*N+n
    int lane = threadIdx.x & 63;
    int b = r / NNPX;
    float4 fn = FN[r];
    const float4* fsb = FS + (size_t)b * NNPX;
    float acc = 0.f;
    for (int k = 0; k < NNPX / 64; ++k) {
        float4 F = fsb[lane + 64 * k];
        acc += __builtin_amdgcn_exp2f(F.x + fn.x * F.y + fn.y * F.z + fn.z * F.w);
    }
    for (int off = 32; off; off >>= 1) acc += __shfl_xor(acc, off);
    if (lane == 0) rowsum[r] = acc;
}

// ---------------- accumulate: P_partial = sum_m w * MQ ----------------
// grid (18, S): blockIdx.x = row-block (1024 rows, thread owns 4),
// blockIdx.y = m-split; each split handles tiles s, s+S, ... of 36 tiles of 256 m.
__global__ __launch_bounds__(256) void k_accum(
        const float4* __restrict__ FS, const float4* __restrict__ FN,
        const float* __restrict__ MQ, float* __restrict__ Ppart, int S) {
    __shared__ float4 QtS[256 * 6];   // [m-in-tile][24 floats padded] transposed MQ
    __shared__ float4 fsS[256];
    int rb = blockIdx.x;              // 0..17
    int s  = blockIdx.y;              // 0..S-1
    int b  = rb / 9;
    int n0 = (rb % 9) * 1024;
    int t  = threadIdx.x;

    float4 fn[4];
    for (int r = 0; r < 4; ++r) fn[r] = FN[b * NNPX + n0 + t + 256 * r];
    float acc[4][LL];
    for (int r = 0; r < 4; ++r)
        for (int l = 0; l < LL; ++l) acc[r][l] = 0.f;

    float* qf = (float*)QtS;
    const float* mqb = MQ + (size_t)b * LL * NNPX;

    for (int tile = s; tile < 36; tile += S) {
        int m0 = tile * 256;
        __syncthreads();
        fsS[t] = FS[b * NNPX + m0 + t];
        for (int l = 0; l < LL; ++l) qf[t * 24 + l] = mqb[(size_t)l * NNPX + m0 + t];
        __syncthreads();
        for (int j = 0; j < 256; ++j) {
            float4 F = fsS[j];
            float w0 = __builtin_amdgcn_exp2f(F.x + fn[0].x * F.y + fn[0].y * F.z + fn[0].z * F.w);
            float w1 = __builtin_amdgcn_exp2f(F.x + fn[1].x * F.y + fn[1].y * F.z + fn[1].z * F.w);
            float w2 = __builtin_amdgcn_exp2f(F.x + fn[2].x * F.y + fn[2].y * F.z + fn[2].z * F.w);
            float w3 = __builtin_amdgcn_exp2f(F.x + fn[3].x * F.y + fn[3].y * F.z + fn[3].z * F.w);
            float4 q0 = QtS[j * 6 + 0], q1 = QtS[j * 6 + 1], q2 = QtS[j * 6 + 2];
            float4 q3 = QtS[j * 6 + 3], q4 = QtS[j * 6 + 4], q5 = QtS[j * 6 + 5];
            float q[LL] = {q0.x, q0.y, q0.z, q0.w, q1.x, q1.y, q1.z, q1.w,
                           q2.x, q2.y, q2.z, q2.w, q3.x, q3.y, q3.z, q3.w,
                           q4.x, q4.y, q4.z, q4.w, q5.x};
            for (int l = 0; l < LL; ++l) {
                acc[0][l] += w0 * q[l];
                acc[1][l] += w1 * q[l];
                acc[2][l] += w2 * q[l];
                acc[3][l] += w3 * q[l];
            }
        }
    }

    for (int r = 0; r < 4; ++r) {
        int n = n0 + t + 256 * r;
        float* pp = Ppart + (((size_t)s * BB + b) * LL) * NNPX + n;
        for (int l = 0; l < LL; ++l) pp[(size_t)l * NNPX] = acc[r][l];
    }
}

// ---------------- reduce partials + softmax + Potts mix ----------------
template <bool LAST>
__global__ __launch_bounds__(256) void k_softmax(
        const float* __restrict__ E0, const float* __restrict__ Ppart,
        const float* __restrict__ rowsum, const float* __restrict__ Mu,
        float* __restrict__ MQ, float* __restrict__ Out, int S) {
    __shared__ float muS[LL * LL];
    for (int i = threadIdx.x; i < LL * LL; i += 256) muS[i] = Mu[i];
    __syncthreads();

    int idx = blockIdx.x * 256 + threadIdx.x;
    int b = idx / NNPX, n = idx % NNPX;

    float P[LL];
    for (int l = 0; l < LL; ++l) P[l] = 0.f;
    for (int s = 0; s < S; ++s) {
        const float* pp = Ppart + (((size_t)s * BB + b) * LL) * NNPX + n;
        for (int l = 0; l < LL; ++l) P[l] += pp[(size_t)l * NNPX];
    }
    float rinv = __builtin_amdgcn_rcpf(rowsum[idx]);

    const float* eb = E0 + (size_t)b * LL * NNPX + n;
    float mx = -1e30f;
    for (int l = 0; l < LL; ++l) {
        P[l] = -(eb[(size_t)l * NNPX] + P[l] * rinv);
        mx = fmaxf(mx, P[l]);
    }
    float ssum = 0.f;
    for (int l = 0; l < LL; ++l) { P[l] = __builtin_amdgcn_exp2f((P[l] - mx) * LOG2E); ssum += P[l]; }
    float rs = __builtin_amdgcn_rcpf(ssum);
    for (int l = 0; l < LL; ++l) P[l] *= rs;

    if (LAST) {
        float* ob = Out + (size_t)b * LL * NNPX + n;
        for (int l = 0; l < LL; ++l) ob[(size_t)l * NNPX] = P[l];
    } else {
        float* mq = MQ + (size_t)b * LL * NNPX + n;
        for (int k = 0; k < LL; ++k) {
            float a = 0.f;
            for (int l = 0; l < LL; ++l) a += muS[k * LL + l] * P[l];
            mq[(size_t)k * NNPX] = a;
        }
    }
}

extern "C" void kernel_launch(void* const* d_in, const int* in_sizes, int n_in,
                              void* d_out, int out_size, void* d_ws, size_t ws_size,
                              hipStream_t stream) {
    const float* E0   = (const float*)d_in[0];
    const float* Refs = (const float*)d_in[1];
    const float* Mu   = (const float*)d_in[2];
    float* out = (float*)d_out;

    char* w = (char*)d_ws;
    size_t off = 0;
    auto alloc = [&](size_t bytes) {
        void* p = w + off;
        off += (bytes + 255) & ~(size_t)255;
        return p;
    };
    float4* FN     = (float4*)alloc((size_t)BB * NNPX * sizeof(float4));
    float4* FS     = (float4*)alloc((size_t)BB * NNPX * sizeof(float4));
    float*  rowsum = (float*) alloc((size_t)BB * NNPX * sizeof(float));
    float*  MQ     = (float*) alloc((size_t)BB * LL * NNPX * sizeof(float));

    // pick largest m-split S (divisor of 36) whose partial buffer fits in ws
    size_t per = (size_t)BB * LL * NNPX * sizeof(float);
    size_t avail = ws_size > off ? ws_size - off : 0;
    int Smax = (int)(avail / (per + 256));
    static const int divs[] = {36, 18, 12, 9, 6, 4, 3, 2, 1};
    int S = 1;
    for (int i = 0; i < 9; ++i) if (divs[i] <= Smax) { S = divs[i]; break; }
    float* Ppart = (float*)alloc((size_t)S * per);

    k_prep<<<BB * NNPX / 256, 256, 0, stream>>>(E0, Refs, Mu, FN, FS, MQ);
    k_rowsum<<<BB * NNPX / 4, 256, 0, stream>>>(FS, FN, rowsum);
    for (int it = 0; it < NITERS; ++it) {
        k_accum<<<dim3(18, S), 256, 0, stream>>>(FS, FN, MQ, Ppart, S);
        if (it == NITERS - 1)
            k_softmax<true><<<BB * NNPX / 256, 256, 0, stream>>>(E0, Ppart, rowsum, Mu, MQ, out, S);
        else
            k_softmax<false><<<BB * NNPX / 256, 256, 0, stream>>>(E0, Ppart, rowsum, Mu, MQ, out, S);
    }
}

// Round 2
// 522.962 us; speedup vs baseline: 1.9032x; 1.9032x over previous
//
#include <hip/hip_runtime.h>
#include <hip/hip_bf16.h>

// CRF-as-RNN mean-field on MI355X. B=2, L=21, C=3, H=W=96, N=9216, NITERS=5.
//
// w[n][m] = exp2(gs[m] + f_n . fs[m])  (log2e pre-scaled; row factor cancels
// under row normalization). rowsum (iteration-invariant) in fp32 once.
// Per iter: P[n][l] = sum_m w[n][m]*MQ[l][m] via bf16 MFMA 16x16x32,
// W generated on the fly into LDS (A-tile), MQ bf16 staged as B-tile.
// msg = P/rowsum; Q = softmax_l(-(E0+msg)); MQ = Mu@Q (bf16).

#define BB 2
#define LL 21
#define NNPX 9216
#define NITERS 5
#define LOG2E 1.4426950408889634f

typedef __attribute__((ext_vector_type(8))) short short8;
typedef __attribute__((ext_vector_type(4))) float f32x4;

static __device__ inline unsigned int pk_bf16(float a, float b) {
    __hip_bfloat162 h = __float22bfloat162_rn(make_float2(a, b));
    unsigned int u;
    __builtin_memcpy(&u, &h, 4);
    return u;
}

// ---------------- prep: features + Q0 + MQ0(bf16) ----------------
__global__ __launch_bounds__(256) void k_prep(
        const float* __restrict__ E0, const float* __restrict__ Refs,
        const float* __restrict__ Mu,
        float4* __restrict__ FN, float4* __restrict__ FS,
        __hip_bfloat16* __restrict__ MQ) {
    __shared__ float muS[LL * LL];
    for (int i = threadIdx.x; i < LL * LL; i += 256) muS[i] = Mu[i];
    __syncthreads();

    int idx = blockIdx.x * 256 + threadIdx.x;      // b*N + n
    int b = idx / NNPX, n = idx % NNPX;

    const float* rb = Refs + (size_t)b * 3 * NNPX + n;
    float r0 = rb[0], r1 = rb[NNPX], r2 = rb[2 * NNPX];
    FN[idx] = make_float4(r0, r1, r2, 0.f);
    float g = -0.5f * (r0 * r0 + r1 * r1 + r2 * r2);
    FS[idx] = make_float4(g * LOG2E, r0 * LOG2E, r1 * LOG2E, r2 * LOG2E);

    const float* eb = E0 + (size_t)b * LL * NNPX + n;
    float x[LL];
    float mx = -1e30f;
    for (int l = 0; l < LL; ++l) { x[l] = -eb[(size_t)l * NNPX]; mx = fmaxf(mx, x[l]); }
    float s = 0.f;
    for (int l = 0; l < LL; ++l) { x[l] = __builtin_amdgcn_exp2f((x[l] - mx) * LOG2E); s += x[l]; }
    float rs = __builtin_amdgcn_rcpf(s);
    for (int l = 0; l < LL; ++l) x[l] *= rs;

    __hip_bfloat16* mq = MQ + (size_t)b * LL * NNPX + n;
    for (int k = 0; k < LL; ++k) {
        float a = 0.f;
        for (int l = 0; l < LL; ++l) a += muS[k * LL + l] * x[l];
        mq[(size_t)k * NNPX] = __float2bfloat16(a);
    }
}

// ---------------- rowsum: one wave per row, fp32 ----------------
__global__ __launch_bounds__(256) void k_rowsum(
        const float4* __restrict__ FS, const float4* __restrict__ FN,
        float* __restrict__ rowsum) {
    int r = blockIdx.x * 4 + (threadIdx.x >> 6);
    int lane = threadIdx.x & 63;
    int b = r / NNPX;
    float4 fn = FN[r];
    const float4* fsb = FS + (size_t)b * NNPX;
    float acc = 0.f;
    for (int k = 0; k < NNPX / 64; ++k) {
        float4 F = fsb[lane + 64 * k];
        acc += __builtin_amdgcn_exp2f(F.x + fn.x * F.y + fn.y * F.z + fn.z * F.w);
    }
    for (int off = 32; off; off >>= 1) acc += __shfl_xor(acc, off);
    if (lane == 0) rowsum[r] = acc;
}

// ---------------- accumulate via MFMA ----------------
// grid (288, S): blockIdx.x = b*144 + n-tile (64 rows), blockIdx.y = m-split.
// m-tiles of 64; split s handles tiles s, s+S, ... of 144.
__global__ __launch_bounds__(256) void k_accum(
        const float4* __restrict__ FS, const float4* __restrict__ FN,
        const unsigned int* __restrict__ MQbf, float* __restrict__ Ppart, int S) {
    // A-tile: W[64 n][72 k] bf16 (stride 72 = pad 8); B-tile: MQ[32 l][72 k] bf16
    __shared__ __align__(16) unsigned short Wlds[64 * 72];
    __shared__ __align__(16) unsigned short Mlds[32 * 72];

    int t = threadIdx.x;
    int rb = blockIdx.x;
    int s  = blockIdx.y;
    int b  = rb / 144;
    int n0 = (rb % 144) * 64;
    int wv = t >> 6, lane = t & 63;

    // zero B-tile (rows 21..31 + pads stay zero forever)
    for (int i = t; i < 32 * 72 / 2; i += 256) ((unsigned int*)Mlds)[i] = 0;

    // w-gen mapping: thread owns n = (t>>4) + 16*i (i<4), m-quad = t&15
    int mq = t & 15;
    int ng = t >> 4;
    float4 fnr[4];
    for (int i = 0; i < 4; ++i) fnr[i] = FN[b * NNPX + n0 + ng + 16 * i];

    f32x4 acc0 = {0.f, 0.f, 0.f, 0.f};   // cols 0..15
    f32x4 acc1 = {0.f, 0.f, 0.f, 0.f};   // cols 16..20 (+pad)

    const unsigned int* mqb = MQbf + (size_t)b * LL * (NNPX / 2);

    for (int tile = s; tile < 144; tile += S) {
        int m0 = tile * 64;
        // per-thread fs for its 4 m (L1-resident, coalesced across 16 threads)
        float4 fsr[4];
        for (int j = 0; j < 4; ++j) fsr[j] = FS[b * NNPX + m0 + 4 * mq + j];

        __syncthreads();   // previous MFMA reads done before overwrite

        // stage MQ B-tile: 21 rows x 32 dwords
        for (int e = t; e < 21 * 32; e += 256) {
            int l = e >> 5, mo = e & 31;
            ((unsigned int*)&Mlds[l * 72])[mo] = mqb[(size_t)l * (NNPX / 2) + m0 / 2 + mo];
        }
        // w-gen: 4 n-rows x 4 m each
        for (int i = 0; i < 4; ++i) {
            float4 f = fnr[i];
            float w0 = __builtin_amdgcn_exp2f(fsr[0].x + f.x * fsr[0].y + f.y * fsr[0].z + f.z * fsr[0].w);
            float w1 = __builtin_amdgcn_exp2f(fsr[1].x + f.x * fsr[1].y + f.y * fsr[1].z + f.z * fsr[1].w);
            float w2 = __builtin_amdgcn_exp2f(fsr[2].x + f.x * fsr[2].y + f.y * fsr[2].z + f.z * fsr[2].w);
            float w3 = __builtin_amdgcn_exp2f(fsr[3].x + f.x * fsr[3].y + f.y * fsr[3].z + f.z * fsr[3].w);
            uint2 pk;
            pk.x = pk_bf16(w0, w1);
            pk.y = pk_bf16(w2, w3);
            int n = ng + 16 * i;
            *(uint2*)&Wlds[n * 72 + 4 * mq] = pk;
        }
        __syncthreads();

        // MFMA: wave wv handles rows n0 + wv*16 .. +16, k = 0..64
        int row = wv * 16 + (lane & 15);
        int kof = (lane >> 4) * 8;
        short8 a0 = *(const short8*)&Wlds[row * 72 + kof];
        short8 a1 = *(const short8*)&Wlds[row * 72 + kof + 32];
        short8 b00 = *(const short8*)&Mlds[(lane & 15) * 72 + kof];
        short8 b01 = *(const short8*)&Mlds[(lane & 15) * 72 + kof + 32];
        short8 b10 = *(const short8*)&Mlds[(16 + (lane & 15)) * 72 + kof];
        short8 b11 = *(const short8*)&Mlds[(16 + (lane & 15)) * 72 + kof + 32];
        acc0 = __builtin_amdgcn_mfma_f32_16x16x32_bf16(a0, b00, acc0, 0, 0, 0);
        acc0 = __builtin_amdgcn_mfma_f32_16x16x32_bf16(a1, b01, acc0, 0, 0, 0);
        acc1 = __builtin_amdgcn_mfma_f32_16x16x32_bf16(a0, b10, acc1, 0, 0, 0);
        acc1 = __builtin_amdgcn_mfma_f32_16x16x32_bf16(a1, b11, acc1, 0, 0, 0);
    }

    // epilogue: C layout col=lane&15, row=(lane>>4)*4+reg
    int col = lane & 15, qr = lane >> 4;
    float* pp = Ppart + ((size_t)(s * BB + b) * LL) * NNPX;
    for (int r = 0; r < 4; ++r) {
        int n = n0 + wv * 16 + qr * 4 + r;
        pp[(size_t)col * NNPX + n] = acc0[r];
        if (col < LL - 16) pp[(size_t)(16 + col) * NNPX + n] = acc1[r];
    }
}

// ---------------- reduce partials + softmax + Potts mix ----------------
template <bool LAST>
__global__ __launch_bounds__(256) void k_softmax(
        const float* __restrict__ E0, const float* __restrict__ Ppart,
        const float* __restrict__ rowsum, const float* __restrict__ Mu,
        __hip_bfloat16* __restrict__ MQ, float* __restrict__ Out, int S) {
    __shared__ float muS[LL * LL];
    for (int i = threadIdx.x; i < LL * LL; i += 256) muS[i] = Mu[i];
    __syncthreads();

    int idx = blockIdx.x * 256 + threadIdx.x;
    int b = idx / NNPX, n = idx % NNPX;

    float P[LL];
    for (int l = 0; l < LL; ++l) P[l] = 0.f;
    for (int s = 0; s < S; ++s) {
        const float* pp = Ppart + ((size_t)(s * BB + b) * LL) * NNPX + n;
        for (int l = 0; l < LL; ++l) P[l] += pp[(size_t)l * NNPX];
    }
    float rinv = __builtin_amdgcn_rcpf(rowsum[idx]);

    const float* eb = E0 + (size_t)b * LL * NNPX + n;
    float mx = -1e30f;
    for (int l = 0; l < LL; ++l) {
        P[l] = -(eb[(size_t)l * NNPX] + P[l] * rinv);
        mx = fmaxf(mx, P[l]);
    }
    float ssum = 0.f;
    for (int l = 0; l < LL; ++l) { P[l] = __builtin_amdgcn_exp2f((P[l] - mx) * LOG2E); ssum += P[l]; }
    float rs = __builtin_amdgcn_rcpf(ssum);
    for (int l = 0; l < LL; ++l) P[l] *= rs;

    if (LAST) {
        float* ob = Out + (size_t)b * LL * NNPX + n;
        for (int l = 0; l < LL; ++l) ob[(size_t)l * NNPX] = P[l];
    } else {
        __hip_bfloat16* mq = MQ + (size_t)b * LL * NNPX + n;
        for (int k = 0; k < LL; ++k) {
            float a = 0.f;
            for (int l = 0; l < LL; ++l) a += muS[k * LL + l] * P[l];
            mq[(size_t)k * NNPX] = __float2bfloat16(a);
        }
    }
}

extern "C" void kernel_launch(void* const* d_in, const int* in_sizes, int n_in,
                              void* d_out, int out_size, void* d_ws, size_t ws_size,
                              hipStream_t stream) {
    const float* E0   = (const float*)d_in[0];
    const float* Refs = (const float*)d_in[1];
    const float* Mu   = (const float*)d_in[2];
    float* out = (float*)d_out;

    char* w = (char*)d_ws;
    size_t off = 0;
    auto alloc = [&](size_t bytes) {
        void* p = w + off;
        off += (bytes + 255) & ~(size_t)255;
        return p;
    };
    float4* FN     = (float4*)alloc((size_t)BB * NNPX * sizeof(float4));
    float4* FS     = (float4*)alloc((size_t)BB * NNPX * sizeof(float4));
    float*  rowsum = (float*) alloc((size_t)BB * NNPX * sizeof(float));
    __hip_bfloat16* MQbf = (__hip_bfloat16*)alloc((size_t)BB * LL * NNPX * sizeof(__hip_bfloat16));

    // m-split S (divisor of 144, capped at 8) whose partial buffer fits in ws
    size_t per = (size_t)BB * LL * NNPX * sizeof(float);
    size_t avail = ws_size > off ? ws_size - off : 0;
    int Smax = (int)(avail / (per + 256));
    static const int divs[] = {8, 6, 4, 3, 2, 1};
    int S = 1;
    for (int i = 0; i < 6; ++i) if (divs[i] <= Smax) { S = divs[i]; break; }
    float* Ppart = (float*)alloc((size_t)S * per);

    k_prep<<<BB * NNPX / 256, 256, 0, stream>>>(E0, Refs, Mu, FN, FS, MQbf);
    k_rowsum<<<BB * NNPX / 4, 256, 0, stream>>>(FS, FN, rowsum);
    for (int it = 0; it < NITERS; ++it) {
        k_accum<<<dim3(288, S), 256, 0, stream>>>(FS, FN, (const unsigned int*)MQbf, Ppart, S);
        if (it == NITERS - 1)
            k_softmax<true><<<BB * NNPX / 256, 256, 0, stream>>>(E0, Ppart, rowsum, Mu, MQbf, out, S);
        else
            k_softmax<false><<<BB * NNPX / 256, 256, 0, stream>>>(E0, Ppart, rowsum, Mu, MQbf, out, S);
    }
}